// Round 24
// baseline (85.767 us; speedup 1.0000x reference)
//
#include <hip/hip_runtime.h>
#include <hip/hip_bf16.h>
#include <math.h>

#define BB 16
#define NTOK 1024
#define CDIM 256
#define HEADS 8
#define HD 32
#define LOG2E 1.4426950408889634f
#define PSHIFT 18.0f

typedef __attribute__((ext_vector_type(8))) _Float16 half8;
typedef __attribute__((ext_vector_type(4))) _Float16 half4v;
typedef __attribute__((ext_vector_type(8))) unsigned short u16x8;
typedef __attribute__((ext_vector_type(4))) unsigned int u32x4;
typedef __attribute__((ext_vector_type(4))) float f32x4;

__device__ __forceinline__ unsigned short f2h(float f) {
  _Float16 h = (_Float16)f;
  return __builtin_bit_cast(unsigned short, h);
}
__device__ __forceinline__ half8 ldh8(const unsigned short* p) {
  return *reinterpret_cast<const half8*>(p);
}
__device__ __forceinline__ void gl_lds16(const void* g, void* l) {
  __builtin_amdgcn_global_load_lds(
      (const __attribute__((address_space(1))) unsigned int*)g,
      (__attribute__((address_space(3))) unsigned int*)l, 16, 0, 0);
}

// ---------------------------------------------------------------------------
// prep_xwb: producers qkv needs. [0,2048): cvt X; [2048,3072): cvt+T W;
// [3072,3136): angle bias.
// ---------------------------------------------------------------------------
__global__ __launch_bounds__(256) void prep_xwb(
    const float* __restrict__ X, const float* __restrict__ Wq,
    const float* __restrict__ Wkv, const float* __restrict__ Wp,
    const float* __restrict__ affine, const float* __restrict__ atab,
    unsigned short* __restrict__ x16, unsigned short* __restrict__ wt16,
    unsigned short* __restrict__ wp16, float* __restrict__ bias) {
  int bid = blockIdx.x;
  if (bid < 2048) {  // ---- cvt X (8/thread)
    size_t base = ((size_t)bid * 256 + threadIdx.x) * 8;
    float4 a = *(const float4*)(X + base);
    float4 b = *(const float4*)(X + base + 4);
    u16x8 o = {f2h(a.x), f2h(a.y), f2h(a.z), f2h(a.w),
               f2h(b.x), f2h(b.y), f2h(b.z), f2h(b.w)};
    *(u16x8*)(x16 + base) = o;
  } else if (bid < 3072) {  // ---- cvt + transpose W
    int idx = (bid - 2048) * 256 + threadIdx.x;
    float val; size_t dst; bool isp = false;
    if (idx < 65536) {
      int k = idx >> 8, n = idx & 255;
      val = Wq[idx]; dst = (size_t)n * 256 + k;
    } else if (idx < 196608) {
      int i2 = idx - 65536;
      int k = i2 >> 9, n2 = i2 & 511;
      val = Wkv[i2]; dst = (size_t)(256 + n2) * 256 + k;
    } else {
      int i3 = idx - 196608;
      int k = i3 >> 8, n = i3 & 255;
      val = Wp[i3]; dst = (size_t)n * 256 + k; isp = true;
    }
    unsigned short h = f2h(val);
    if (isp) wp16[dst] = h; else wt16[dst] = h;
  } else {  // ---- angle bias
    int idx = (bid - 3072) * 256 + threadIdx.x;
    if (idx >= BB * NTOK) return;
    int b = idx >> 10, n = idx & (NTOK - 1);
    float cx = (float)(n & 31);
    float cy = (float)(n >> 5);
    const float* A = affine + b * 6;
    float egx = fmaf(A[0], 16.f, fmaf(A[1], 16.f, A[2]));
    float egy = fmaf(A[3], 16.f, fmaf(A[4], 16.f, A[5]));
    float ang = atan2f(cy - egy, cx - egx);
    float t = (ang + 3.14159265358979323846f) *
              (1.f / (2.f * 3.14159265358979323846f)) * 4.f;
    int bin = (int)t;
    bin = bin < 0 ? 0 : (bin > 4 ? 4 : bin);
    for (int h = 0; h < HEADS; ++h) {
      float a = atab[bin * HEADS + h];
      float s = 1.f / (1.f + __expf(-a));
      bias[((size_t)b * HEADS + h) * NTOK + n] = 1.f + s;
    }
  }
}

// ---------------------------------------------------------------------------
// QKV projection FUSED with mask-fragment prep (round-23 structure):
//  blocks [0,768): fp16 MFMA GEMM; [768,2816): mask -> fp16 fragment slabs.
// ---------------------------------------------------------------------------
__global__ __launch_bounds__(512, 4) void gemm_qkv16(
    const unsigned short* __restrict__ x16, const unsigned short* __restrict__ wt16,
    const float* __restrict__ bq, const float* __restrict__ bkv,
    const float* __restrict__ bias, const float* __restrict__ mask,
    unsigned short* __restrict__ q16, unsigned short* __restrict__ k16,
    unsigned short* __restrict__ vt16, unsigned short* __restrict__ mF16) {
  __shared__ __align__(16) unsigned short SM[16384];  // 32 KB multi-use
  int bid = blockIdx.x;
  if (bid >= 768) {  // ---- mask prep branch (1 float4/thread, 512 thr)
    int idx = (bid - 768) * 512 + threadIdx.x;   // 0 .. 1,048,575
    int b4 = idx >> 18;
    int rem = idx & 262143;
    int q = rem >> 8;
    int k = (rem & 255) * 4;
    float4 v = *(const float4*)(mask + ((size_t)b4 * NTOK + q) * NTOK + k);
    int kt = k >> 5;
    int ins0 = (k & 31) >> 1;
    int gw = (ins0 >> 2) ^ ((q >> 2) & 3);
    int io = ins0 & 3;
    size_t off = (size_t)q * 16 + gw * 4 + io;
    size_t slabE = ((size_t)(b4 * 64 + kt * 2)) * 16384;
    unsigned eP = (unsigned)f2h(v.x * LOG2E) |
                  ((unsigned)f2h(v.z * LOG2E) << 16);
    unsigned oP = (unsigned)f2h(v.y * LOG2E) |
                  ((unsigned)f2h(v.w * LOG2E) << 16);
    *(unsigned*)(mF16 + slabE + off) = eP;
    *(unsigned*)(mF16 + slabE + 16384 + off) = oP;
    return;
  }
  unsigned short* Xs = SM;            // [2][4096]
  unsigned short* Ws = SM + 8192;     // [2][4096]
  int tid = threadIdx.x;
  int w = tid >> 6, l = tid & 63;
  int row16 = l & 15, grp = l >> 4;
  int xcd = bid & 7, local = bid >> 3;        // 0..95
  int jb = local % 6, mb = xcd * 16 + local / 6;
  int j0 = jb * 128, m0 = mb * 128;
  int wm = w >> 1, wn = w & 1;

  auto stg = [&](int nb, int kt) {  // 1KB chunk per operand per wave
    int k0s = kt * 32;
    int row = w * 16 + (l >> 2);
    int ge = (((l & 3) * 16) ^ ((row & 3) << 4)) >> 1;
    gl_lds16(x16 + (size_t)(m0 + row) * 256 + k0s + ge, Xs + nb * 4096 + w * 512);
    gl_lds16(wt16 + (size_t)(j0 + row) * 256 + k0s + ge, Ws + nb * 4096 + w * 512);
  };
  auto off16 = [&](int row, int g) {
    return row * 32 + ((((g * 16) ^ ((row & 3) << 4))) >> 1);
  };

  stg(0, 0);
  __syncthreads();

  f32x4 acc[2][4];
#pragma unroll
  for (int i = 0; i < 2; ++i)
#pragma unroll
    for (int c = 0; c < 4; ++c) acc[i][c] = (f32x4){0.f, 0.f, 0.f, 0.f};

  for (int kt = 0; kt < 8; ++kt) {
    int cur = kt & 1;
    if (kt < 7) stg(cur ^ 1, kt + 1);
    half8 a0 = ldh8(Xs + cur * 4096 + off16(wm * 32 + row16, grp));
    half8 a1 = ldh8(Xs + cur * 4096 + off16(wm * 32 + 16 + row16, grp));
#pragma unroll
    for (int c = 0; c < 4; ++c) {
      half8 bh = ldh8(Ws + cur * 4096 + off16(wn * 64 + c * 16 + row16, grp));
      acc[0][c] = __builtin_amdgcn_mfma_f32_16x16x32_f16(a0, bh, acc[0][c], 0, 0, 0);
      acc[1][c] = __builtin_amdgcn_mfma_f32_16x16x32_f16(a1, bh, acc[1][c], 0, 0, 0);
    }
    __syncthreads();
  }

  // epilogue: bounce through SM as u16 [64][136], two 64-row halves
  const float scaleq = 0.17677669529663687f * LOG2E;
  int half_mine = wm >> 1;
  for (int half = 0; half < 2; ++half) {
    if (half_mine == half) {
#pragma unroll
      for (int i = 0; i < 2; ++i) {
#pragma unroll
        for (int c = 0; c < 4; ++c) {
          int col = wn * 64 + c * 16 + row16;
          int jg = j0 + col;
#pragma unroll
          for (int r = 0; r < 4; ++r) {
            int rowl = (wm & 1) * 32 + i * 16 + grp * 4 + r;
            int m = m0 + half * 64 + rowl;
            int b = m >> 10, n = m & (NTOK - 1);
            float val = acc[i][c][r];
            unsigned short o;
            if (jb < 2)
              o = f2h((val + bq[jg]) * scaleq *
                      bias[((size_t)b * HEADS + (jg >> 5)) * NTOK + n]);
            else
              o = f2h(val + bkv[jg - CDIM]);
            SM[rowl * 136 + col] = o;
          }
        }
      }
    }
    __syncthreads();
    if (jb < 4) {
#pragma unroll
      for (int it = 0; it < 2; ++it) {
        int lin = it * 512 + tid;
        int rowb = lin >> 4, oct = lin & 15;
        u16x8 v = *(const u16x8*)&SM[rowb * 136 + oct * 8];
        int m = m0 + half * 64 + rowb;
        int b = m >> 10, n = m & (NTOK - 1);
        int jg = j0 + oct * 8;
        unsigned short* dst; int h, d;
        if (jb < 2) { h = jg >> 5; d = jg & 31; dst = q16; }
        else { int c2 = jg - CDIM; h = c2 >> 5; d = c2 & 31; dst = k16; }
        *(u16x8*)(dst + (((size_t)b * HEADS + h) * NTOK + n) * HD + d) = v;
      }
    } else {
#pragma unroll
      for (int it = 0; it < 2; ++it) {
        int lin = it * 512 + tid;
        int noct = lin >> 7, jl = lin & 127;
        u16x8 v;
#pragma unroll
        for (int e = 0; e < 8; ++e) v[e] = SM[(noct * 8 + e) * 136 + jl];
        int c3 = j0 + jl - 2 * CDIM;
        int h = c3 >> 5, d = c3 & 31;
        int n0 = m0 + half * 64 + noct * 8;
        int b = n0 >> 10, nn = n0 & (NTOK - 1);
        *(u16x8*)(vt16 + (((size_t)b * HEADS + h) * HD + d) * NTOK + nn) = v;
      }
    }
    __syncthreads();
  }
}

// ---------------------------------------------------------------------------
// Flash attention, TLP-doubled: block = (b, 64q, head-group of TWO).
// Grid 1024 = 4 blocks/CU. 8 waves = 2 heads (hl=w&1) x 4 q-sixteenths
// (role=w>>1). LDS 24.6 KB. Staging roles per head: {K0,K1,V0,V1} 1KB
// chunks; mask's 4 chunks staged by the hl==0 waves. Same even/odd K-perm,
// fragment-ordered fp16 mask in the C-path, in-register P.
// ---------------------------------------------------------------------------
__global__ __launch_bounds__(512, 8) void attn16(
    const unsigned short* __restrict__ q16, const unsigned short* __restrict__ k16,
    const unsigned short* __restrict__ vt16, const unsigned short* __restrict__ mF16,
    unsigned short* __restrict__ ao16) {
  __shared__ __align__(16) unsigned short KT[2][2][1024];  // [buf][head][32k x 32d]
  __shared__ __align__(16) unsigned short VT[2][2][1024];  // [buf][head][32d x 32k]
  __shared__ __align__(16) unsigned short MT[2][2][1024];  // [buf][slab][64q x 16h]

  int tid = threadIdx.x;
  int w = tid >> 6, l = tid & 63;
  int row16 = l & 15, grp = l >> 4;
  int bid = blockIdx.x;
  // slab group g in [0,64): blocks sharing a mask slab colocate at bid%8
  int g = (bid >> 7) * 8 + (bid & 7);
  int inner = (bid >> 3) & 15;
  int qt = g >> 2, b4 = g & 3;
  int brep = inner >> 2, hg = inner & 3;
  int b = brep * 4 + b4;
  int hl = w & 1, role = w >> 1;
  int head = hg * 2 + hl;
  int bh = b * HEADS + head;
  int q0g = qt * 64;

  // Q B-operand: this wave's 16-q fragment
  half8 bq16 = ldh8(q16 + ((size_t)bh * NTOK + q0g + role * 16 + row16) * HD +
                    grp * 8);

  const unsigned short* mFb = mF16 + (size_t)b4 * 64 * 16384;

  f32x4 acc[2];
  acc[0] = (f32x4){0.f, 0.f, 0.f, 0.f};
  acc[1] = (f32x4){0.f, 0.f, 0.f, 0.f};
  float lsum = 0.f;
  const f32x4 c18 = (f32x4){-PSHIFT, -PSHIFT, -PSHIFT, -PSHIFT};

  auto off32 = [&](int row, int gg) {
    return row * 32 + ((gg ^ ((row >> 1) & 3)) << 3);
  };

  auto stage = [&](int nb, int kt2) {
    int k0n = (kt2 & 31) * 32;
    if (role < 2) {  // K chunk c = role: LDS row r = c*16+(l>>2), key 2*(l>>2)+c
      int c = role;
      int r = c * 16 + (l >> 2);
      int key = 2 * (l >> 2) + c;
      int sk = (l & 3) ^ ((r >> 1) & 3);
      gl_lds16(k16 + ((size_t)bh * NTOK + k0n + key) * HD + sk * 8,
               &KT[nb][hl][c * 512]);
    } else {         // V chunk c = role-2: d-rows c*16..+15
      int c = role - 2;
      int dl = c * 16 + (l >> 2);
      int sv = (l & 3) ^ ((dl >> 1) & 3);
      gl_lds16(vt16 + ((size_t)bh * HD + dl) * NTOK + k0n + sv * 8,
               &VT[nb][hl][c * 512]);
    }
    if (hl == 0) {   // mask chunks: 2 slabs x 2 chunks, linear copy
      int slab = role >> 1, ch = role & 1;
      gl_lds16(mFb + (size_t)((kt2 & 31) * 2 + slab) * 16384 + q0g * 16 +
                   ch * 512 + l * 8,
               &MT[nb][slab][ch * 512]);
    }
  };

  stage(0, 0);
  __syncthreads();

  for (int kt = 0; kt < 32; ++kt) {
    int cur = kt & 1;
    if (kt < 31) stage(cur ^ 1, kt + 1);

    half8 kf0 = ldh8(&KT[cur][hl][off32(row16, grp)]);
    half8 kf1 = ldh8(&KT[cur][hl][off32(16 + row16, grp)]);
    half8 v0 = ldh8(&VT[cur][hl][off32(row16, grp)]);
    half8 v1 = ldh8(&VT[cur][hl][off32(16 + row16, grp)]);

    int qr = role * 16 + row16;                    // local q row 0..63
    int g2 = grp ^ ((qr >> 2) & 3);
    half4v me = *(const half4v*)&MT[cur][0][qr * 16 + g2 * 4];
    half4v mo = *(const half4v*)&MT[cur][1][qr * 16 + g2 * 4];
    f32x4 s0 = __builtin_amdgcn_mfma_f32_16x16x32_f16(kf0, bq16, c18, 0, 0, 0);
    f32x4 s1 = __builtin_amdgcn_mfma_f32_16x16x32_f16(kf1, bq16, c18, 0, 0, 0);
    f32x4 e0, e1;
#pragma unroll
    for (int r = 0; r < 4; ++r) {
      e0[r] = __builtin_amdgcn_exp2f(s0[r] + (float)me[r]);
      e1[r] = __builtin_amdgcn_exp2f(s1[r] + (float)mo[r]);
    }
    lsum += ((e0[0] + e1[0]) + (e0[1] + e1[1])) +
            ((e0[2] + e1[2]) + (e0[3] + e1[3]));
    u32x4 pk;
#pragma unroll
    for (int r = 0; r < 4; ++r)
      pk[r] = __builtin_bit_cast(unsigned,
                                 __builtin_amdgcn_cvt_pkrtz(e0[r], e1[r]));
    half8 pa = __builtin_bit_cast(half8, pk);  // keys 8grp..8grp+7
    acc[0] = __builtin_amdgcn_mfma_f32_16x16x32_f16(pa, v0, acc[0], 0, 0, 0);
    acc[1] = __builtin_amdgcn_mfma_f32_16x16x32_f16(pa, v1, acc[1], 0, 0, 0);
    __syncthreads();
  }

  // reduce lsum across the 4 grp slices (value depends only on row16)
  lsum += __shfl_xor(lsum, 16);
  lsum += __shfl_xor(lsum, 32);
#pragma unroll
  for (int r = 0; r < 4; ++r) {
    float lr = __shfl(lsum, grp * 4 + r, 16);
    float inv = 1.f / lr;
    int qrow = q0g + role * 16 + grp * 4 + r;
    size_t obase = ((size_t)b * NTOK + qrow) * CDIM + head * HD;
    ao16[obase + row16] = f2h(acc[0][r] * inv);
    ao16[obase + 16 + row16] = f2h(acc[1][r] * inv);
  }
}

// ---------------------------------------------------------------------------
// Output projection: round-12 structure.
// ---------------------------------------------------------------------------
__global__ __launch_bounds__(512, 4) void gemm_out16(
    const unsigned short* __restrict__ a16, const unsigned short* __restrict__ wp16,
    const float* __restrict__ bp, float* __restrict__ out) {
  __shared__ __align__(16) unsigned short SM[16384];
  unsigned short* Xs = SM;
  unsigned short* Ws = SM + 8192;
  int tid = threadIdx.x;
  int w = tid >> 6, l = tid & 63;
  int row16 = l & 15, grp = l >> 4;
  int bid = blockIdx.x;
  int xcd = bid & 7, local = bid >> 3;
  int jb = local & 1, mb = xcd * 16 + (local >> 1);
  int j0 = jb * 128, m0 = mb * 128;
  int wm = w >> 1, wn = w & 1;

  auto stg = [&](int nb, int kt) {
    int k0s = kt * 32;
    int row = w * 16 + (l >> 2);
    int ge = (((l & 3) * 16) ^ ((row & 3) << 4)) >> 1;
    gl_lds16(a16 + (size_t)(m0 + row) * 256 + k0s + ge, Xs + nb * 4096 + w * 512);
    gl_lds16(wp16 + (size_t)(j0 + row) * 256 + k0s + ge, Ws + nb * 4096 + w * 512);
  };
  auto off16 = [&](int row, int g) {
    return row * 32 + ((((g * 16) ^ ((row & 3) << 4))) >> 1);
  };

  stg(0, 0);
  __syncthreads();

  f32x4 acc[2][4];
#pragma unroll
  for (int i = 0; i < 2; ++i)
#pragma unroll
    for (int c = 0; c < 4; ++c) acc[i][c] = (f32x4){0.f, 0.f, 0.f, 0.f};

  for (int kt = 0; kt < 8; ++kt) {
    int cur = kt & 1;
    if (kt < 7) stg(cur ^ 1, kt + 1);
    half8 a0 = ldh8(Xs + cur * 4096 + off16(wm * 32 + row16, grp));
    half8 a1 = ldh8(Xs + cur * 4096 + off16(wm * 32 + 16 + row16, grp));
#pragma unroll
    for (int c = 0; c < 4; ++c) {
      half8 bh = ldh8(Ws + cur * 4096 + off16(wn * 64 + c * 16 + row16, grp));
      acc[0][c] = __builtin_amdgcn_mfma_f32_16x16x32_f16(a0, bh, acc[0][c], 0, 0, 0);
      acc[1][c] = __builtin_amdgcn_mfma_f32_16x16x32_f16(a1, bh, acc[1][c], 0, 0, 0);
    }
    __syncthreads();
  }

#pragma unroll
  for (int i = 0; i < 2; ++i) {
    int ng = m0 + wm * 32 + i * 16 + grp * 4;
#pragma unroll
    for (int c = 0; c < 4; ++c) {
      int jg = j0 + wn * 64 + c * 16 + row16;
      float bias = bp[jg];
#pragma unroll
      for (int r = 0; r < 4; ++r) {
        out[(size_t)(ng + r) * CDIM + jg] = acc[i][c][r] + bias;
      }
    }
  }
}

// ---------------------------------------------------------------------------
extern "C" void kernel_launch(void* const* d_in, const int* in_sizes, int n_in,
                              void* d_out, int out_size, void* d_ws,
                              size_t ws_size, hipStream_t stream) {
  const float* x = (const float*)d_in[0];
  const float* mask = (const float*)d_in[1];
  const float* affine = (const float*)d_in[2];
  const float* Wq = (const float*)d_in[3];
  const float* bq = (const float*)d_in[4];
  const float* Wkv = (const float*)d_in[5];
  const float* bkv = (const float*)d_in[6];
  const float* Wp = (const float*)d_in[7];
  const float* bp = (const float*)d_in[8];
  const float* atab = (const float*)d_in[9];
  float* out = (float*)d_out;

  const size_t bhnd = (size_t)BB * HEADS * NTOK * HD;  // 4,194,304
  unsigned short* q16 = (unsigned short*)d_ws;
  unsigned short* k16 = q16 + bhnd;
  unsigned short* vt16 = k16 + bhnd;
  unsigned short* x16 = vt16 + bhnd;     // aliased as ao16 after qkv
  unsigned short* wt16 = x16 + bhnd;     // 768*256
  unsigned short* wp16 = wt16 + 768 * 256;
  unsigned short* mF16 = wp16 + 256 * 256;     // 4*64*16384 u16 = 8MB
  float* bias = (float*)(mF16 + (size_t)4 * 64 * 16384);

  prep_xwb<<<3136, 256, 0, stream>>>(x, Wq, Wkv, Wp, affine, atab, x16, wt16,
                                     wp16, bias);
  gemm_qkv16<<<2816, 512, 0, stream>>>(x16, wt16, bq, bkv, bias, mask, q16,
                                       k16, vt16, mF16);
  attn16<<<1024, 512, 0, stream>>>(q16, k16, vt16, mF16, x16);
  gemm_out16<<<256, 512, 0, stream>>>(x16, wp16, bp, out);
}

// Round 25
// 84.201 us; speedup vs baseline: 1.0186x; 1.0186x over previous
//
#include <hip/hip_runtime.h>
#include <hip/hip_bf16.h>
#include <math.h>

#define BB 16
#define NTOK 1024
#define CDIM 256
#define HEADS 8
#define HD 32
#define LOG2E 1.4426950408889634f
#define PSHIFT 18.0f

typedef __attribute__((ext_vector_type(8))) _Float16 half8;
typedef __attribute__((ext_vector_type(4))) _Float16 half4v;
typedef __attribute__((ext_vector_type(8))) unsigned short u16x8;
typedef __attribute__((ext_vector_type(4))) unsigned int u32x4;
typedef __attribute__((ext_vector_type(4))) float f32x4;

__device__ __forceinline__ unsigned short f2h(float f) {
  _Float16 h = (_Float16)f;
  return __builtin_bit_cast(unsigned short, h);
}
__device__ __forceinline__ half8 ldh8(const unsigned short* p) {
  return *reinterpret_cast<const half8*>(p);
}
__device__ __forceinline__ void gl_lds16(const void* g, void* l) {
  __builtin_amdgcn_global_load_lds(
      (const __attribute__((address_space(1))) unsigned int*)g,
      (__attribute__((address_space(3))) unsigned int*)l, 16, 0, 0);
}

// ---------------------------------------------------------------------------
// prep_xwb: producers qkv needs. [0,2048): cvt X; [2048,3072): cvt+T W;
// [3072,3136): angle bias.
// ---------------------------------------------------------------------------
__global__ __launch_bounds__(256) void prep_xwb(
    const float* __restrict__ X, const float* __restrict__ Wq,
    const float* __restrict__ Wkv, const float* __restrict__ Wp,
    const float* __restrict__ affine, const float* __restrict__ atab,
    unsigned short* __restrict__ x16, unsigned short* __restrict__ wt16,
    unsigned short* __restrict__ wp16, float* __restrict__ bias) {
  int bid = blockIdx.x;
  if (bid < 2048) {  // ---- cvt X (8/thread)
    size_t base = ((size_t)bid * 256 + threadIdx.x) * 8;
    float4 a = *(const float4*)(X + base);
    float4 b = *(const float4*)(X + base + 4);
    u16x8 o = {f2h(a.x), f2h(a.y), f2h(a.z), f2h(a.w),
               f2h(b.x), f2h(b.y), f2h(b.z), f2h(b.w)};
    *(u16x8*)(x16 + base) = o;
  } else if (bid < 3072) {  // ---- cvt + transpose W
    int idx = (bid - 2048) * 256 + threadIdx.x;
    float val; size_t dst; bool isp = false;
    if (idx < 65536) {
      int k = idx >> 8, n = idx & 255;
      val = Wq[idx]; dst = (size_t)n * 256 + k;
    } else if (idx < 196608) {
      int i2 = idx - 65536;
      int k = i2 >> 9, n2 = i2 & 511;
      val = Wkv[i2]; dst = (size_t)(256 + n2) * 256 + k;
    } else {
      int i3 = idx - 196608;
      int k = i3 >> 8, n = i3 & 255;
      val = Wp[i3]; dst = (size_t)n * 256 + k; isp = true;
    }
    unsigned short h = f2h(val);
    if (isp) wp16[dst] = h; else wt16[dst] = h;
  } else {  // ---- angle bias
    int idx = (bid - 3072) * 256 + threadIdx.x;
    if (idx >= BB * NTOK) return;
    int b = idx >> 10, n = idx & (NTOK - 1);
    float cx = (float)(n & 31);
    float cy = (float)(n >> 5);
    const float* A = affine + b * 6;
    float egx = fmaf(A[0], 16.f, fmaf(A[1], 16.f, A[2]));
    float egy = fmaf(A[3], 16.f, fmaf(A[4], 16.f, A[5]));
    float ang = atan2f(cy - egy, cx - egx);
    float t = (ang + 3.14159265358979323846f) *
              (1.f / (2.f * 3.14159265358979323846f)) * 4.f;
    int bin = (int)t;
    bin = bin < 0 ? 0 : (bin > 4 ? 4 : bin);
    for (int h = 0; h < HEADS; ++h) {
      float a = atab[bin * HEADS + h];
      float s = 1.f / (1.f + __expf(-a));
      bias[((size_t)b * HEADS + h) * NTOK + n] = 1.f + s;
    }
  }
}

// ---------------------------------------------------------------------------
// QKV projection FUSED with mask-fragment prep (round-23 structure):
//  blocks [0,768): fp16 MFMA GEMM; [768,2816): mask -> fp16 fragment slabs.
// ---------------------------------------------------------------------------
__global__ __launch_bounds__(512, 4) void gemm_qkv16(
    const unsigned short* __restrict__ x16, const unsigned short* __restrict__ wt16,
    const float* __restrict__ bq, const float* __restrict__ bkv,
    const float* __restrict__ bias, const float* __restrict__ mask,
    unsigned short* __restrict__ q16, unsigned short* __restrict__ k16,
    unsigned short* __restrict__ vt16, unsigned short* __restrict__ mF16) {
  __shared__ __align__(16) unsigned short SM[16384];  // 32 KB multi-use
  int bid = blockIdx.x;
  if (bid >= 768) {  // ---- mask prep branch (1 float4/thread, 512 thr)
    int idx = (bid - 768) * 512 + threadIdx.x;   // 0 .. 1,048,575
    int b4 = idx >> 18;
    int rem = idx & 262143;
    int q = rem >> 8;
    int k = (rem & 255) * 4;
    float4 v = *(const float4*)(mask + ((size_t)b4 * NTOK + q) * NTOK + k);
    int kt = k >> 5;
    int ins0 = (k & 31) >> 1;
    int gw = (ins0 >> 2) ^ ((q >> 2) & 3);
    int io = ins0 & 3;
    size_t off = (size_t)q * 16 + gw * 4 + io;
    size_t slabE = ((size_t)(b4 * 64 + kt * 2)) * 16384;
    unsigned eP = (unsigned)f2h(v.x * LOG2E) |
                  ((unsigned)f2h(v.z * LOG2E) << 16);
    unsigned oP = (unsigned)f2h(v.y * LOG2E) |
                  ((unsigned)f2h(v.w * LOG2E) << 16);
    *(unsigned*)(mF16 + slabE + off) = eP;
    *(unsigned*)(mF16 + slabE + 16384 + off) = oP;
    return;
  }
  unsigned short* Xs = SM;            // [2][4096]
  unsigned short* Ws = SM + 8192;     // [2][4096]
  int tid = threadIdx.x;
  int w = tid >> 6, l = tid & 63;
  int row16 = l & 15, grp = l >> 4;
  int xcd = bid & 7, local = bid >> 3;        // 0..95
  int jb = local % 6, mb = xcd * 16 + local / 6;
  int j0 = jb * 128, m0 = mb * 128;
  int wm = w >> 1, wn = w & 1;

  auto stg = [&](int nb, int kt) {  // 1KB chunk per operand per wave
    int k0s = kt * 32;
    int row = w * 16 + (l >> 2);
    int ge = (((l & 3) * 16) ^ ((row & 3) << 4)) >> 1;
    gl_lds16(x16 + (size_t)(m0 + row) * 256 + k0s + ge, Xs + nb * 4096 + w * 512);
    gl_lds16(wt16 + (size_t)(j0 + row) * 256 + k0s + ge, Ws + nb * 4096 + w * 512);
  };
  auto off16 = [&](int row, int g) {
    return row * 32 + ((((g * 16) ^ ((row & 3) << 4))) >> 1);
  };

  stg(0, 0);
  __syncthreads();

  f32x4 acc[2][4];
#pragma unroll
  for (int i = 0; i < 2; ++i)
#pragma unroll
    for (int c = 0; c < 4; ++c) acc[i][c] = (f32x4){0.f, 0.f, 0.f, 0.f};

  for (int kt = 0; kt < 8; ++kt) {
    int cur = kt & 1;
    if (kt < 7) stg(cur ^ 1, kt + 1);
    half8 a0 = ldh8(Xs + cur * 4096 + off16(wm * 32 + row16, grp));
    half8 a1 = ldh8(Xs + cur * 4096 + off16(wm * 32 + 16 + row16, grp));
#pragma unroll
    for (int c = 0; c < 4; ++c) {
      half8 bh = ldh8(Ws + cur * 4096 + off16(wn * 64 + c * 16 + row16, grp));
      acc[0][c] = __builtin_amdgcn_mfma_f32_16x16x32_f16(a0, bh, acc[0][c], 0, 0, 0);
      acc[1][c] = __builtin_amdgcn_mfma_f32_16x16x32_f16(a1, bh, acc[1][c], 0, 0, 0);
    }
    __syncthreads();
  }

  // epilogue: bounce through SM as u16 [64][136], two 64-row halves
  const float scaleq = 0.17677669529663687f * LOG2E;
  int half_mine = wm >> 1;
  for (int half = 0; half < 2; ++half) {
    if (half_mine == half) {
#pragma unroll
      for (int i = 0; i < 2; ++i) {
#pragma unroll
        for (int c = 0; c < 4; ++c) {
          int col = wn * 64 + c * 16 + row16;
          int jg = j0 + col;
#pragma unroll
          for (int r = 0; r < 4; ++r) {
            int rowl = (wm & 1) * 32 + i * 16 + grp * 4 + r;
            int m = m0 + half * 64 + rowl;
            int b = m >> 10, n = m & (NTOK - 1);
            float val = acc[i][c][r];
            unsigned short o;
            if (jb < 2)
              o = f2h((val + bq[jg]) * scaleq *
                      bias[((size_t)b * HEADS + (jg >> 5)) * NTOK + n]);
            else
              o = f2h(val + bkv[jg - CDIM]);
            SM[rowl * 136 + col] = o;
          }
        }
      }
    }
    __syncthreads();
    if (jb < 4) {
#pragma unroll
      for (int it = 0; it < 2; ++it) {
        int lin = it * 512 + tid;
        int rowb = lin >> 4, oct = lin & 15;
        u16x8 v = *(const u16x8*)&SM[rowb * 136 + oct * 8];
        int m = m0 + half * 64 + rowb;
        int b = m >> 10, n = m & (NTOK - 1);
        int jg = j0 + oct * 8;
        unsigned short* dst; int h, d;
        if (jb < 2) { h = jg >> 5; d = jg & 31; dst = q16; }
        else { int c2 = jg - CDIM; h = c2 >> 5; d = c2 & 31; dst = k16; }
        *(u16x8*)(dst + (((size_t)b * HEADS + h) * NTOK + n) * HD + d) = v;
      }
    } else {
#pragma unroll
      for (int it = 0; it < 2; ++it) {
        int lin = it * 512 + tid;
        int noct = lin >> 7, jl = lin & 127;
        u16x8 v;
#pragma unroll
        for (int e = 0; e < 8; ++e) v[e] = SM[(noct * 8 + e) * 136 + jl];
        int c3 = j0 + jl - 2 * CDIM;
        int h = c3 >> 5, d = c3 & 31;
        int n0 = m0 + half * 64 + noct * 8;
        int b = n0 >> 10, nn = n0 & (NTOK - 1);
        *(u16x8*)(vt16 + (((size_t)b * HEADS + h) * HD + d) * NTOK + nn) = v;
      }
    }
    __syncthreads();
  }
}

// ---------------------------------------------------------------------------
// Flash attention (round-24 structure: head-group of 2, grid 1024) with the
// softmax denominator computed on the MFMA pipe: accL = mfma(pa, ones, accL)
// accumulates exact per-q row-sums of P in the SAME layout as the PV
// accumulator -> zero VALU adds, zero cross-lane shuffles for lsum.
// ---------------------------------------------------------------------------
__global__ __launch_bounds__(512, 8) void attn16(
    const unsigned short* __restrict__ q16, const unsigned short* __restrict__ k16,
    const unsigned short* __restrict__ vt16, const unsigned short* __restrict__ mF16,
    unsigned short* __restrict__ ao16) {
  __shared__ __align__(16) unsigned short KT[2][2][1024];  // [buf][head][32k x 32d]
  __shared__ __align__(16) unsigned short VT[2][2][1024];  // [buf][head][32d x 32k]
  __shared__ __align__(16) unsigned short MT[2][2][1024];  // [buf][slab][64q x 16h]

  int tid = threadIdx.x;
  int w = tid >> 6, l = tid & 63;
  int row16 = l & 15, grp = l >> 4;
  int bid = blockIdx.x;
  int g = (bid >> 7) * 8 + (bid & 7);
  int inner = (bid >> 3) & 15;
  int qt = g >> 2, b4 = g & 3;
  int brep = inner >> 2, hg = inner & 3;
  int b = brep * 4 + b4;
  int hl = w & 1, role = w >> 1;
  int head = hg * 2 + hl;
  int bh = b * HEADS + head;
  int q0g = qt * 64;

  // Q B-operand: this wave's 16-q fragment
  half8 bq16 = ldh8(q16 + ((size_t)bh * NTOK + q0g + role * 16 + row16) * HD +
                    grp * 8);

  const unsigned short* mFb = mF16 + (size_t)b4 * 64 * 16384;

  f32x4 acc[2];
  acc[0] = (f32x4){0.f, 0.f, 0.f, 0.f};
  acc[1] = (f32x4){0.f, 0.f, 0.f, 0.f};
  f32x4 accL = (f32x4){0.f, 0.f, 0.f, 0.f};   // lsum per q (MFMA-accumulated)
  const f32x4 c18 = (f32x4){-PSHIFT, -PSHIFT, -PSHIFT, -PSHIFT};
  const _Float16 one = (_Float16)1.0f;
  const half8 vones = {one, one, one, one, one, one, one, one};

  auto off32 = [&](int row, int gg) {
    return row * 32 + ((gg ^ ((row >> 1) & 3)) << 3);
  };

  auto stage = [&](int nb, int kt2) {
    int k0n = (kt2 & 31) * 32;
    if (role < 2) {  // K chunk c = role: LDS row r = c*16+(l>>2), key 2*(l>>2)+c
      int c = role;
      int r = c * 16 + (l >> 2);
      int key = 2 * (l >> 2) + c;
      int sk = (l & 3) ^ ((r >> 1) & 3);
      gl_lds16(k16 + ((size_t)bh * NTOK + k0n + key) * HD + sk * 8,
               &KT[nb][hl][c * 512]);
    } else {         // V chunk c = role-2: d-rows c*16..+15
      int c = role - 2;
      int dl = c * 16 + (l >> 2);
      int sv = (l & 3) ^ ((dl >> 1) & 3);
      gl_lds16(vt16 + ((size_t)bh * HD + dl) * NTOK + k0n + sv * 8,
               &VT[nb][hl][c * 512]);
    }
    if (hl == 0) {   // mask chunks: 2 slabs x 2 chunks, linear copy
      int slab = role >> 1, ch = role & 1;
      gl_lds16(mFb + (size_t)((kt2 & 31) * 2 + slab) * 16384 + q0g * 16 +
                   ch * 512 + l * 8,
               &MT[nb][slab][ch * 512]);
    }
  };

  stage(0, 0);
  __syncthreads();

  for (int kt = 0; kt < 32; ++kt) {
    int cur = kt & 1;
    if (kt < 31) stage(cur ^ 1, kt + 1);

    half8 kf0 = ldh8(&KT[cur][hl][off32(row16, grp)]);
    half8 kf1 = ldh8(&KT[cur][hl][off32(16 + row16, grp)]);
    half8 v0 = ldh8(&VT[cur][hl][off32(row16, grp)]);
    half8 v1 = ldh8(&VT[cur][hl][off32(16 + row16, grp)]);

    int qr = role * 16 + row16;                    // local q row 0..63
    int g2 = grp ^ ((qr >> 2) & 3);
    half4v me = *(const half4v*)&MT[cur][0][qr * 16 + g2 * 4];
    half4v mo = *(const half4v*)&MT[cur][1][qr * 16 + g2 * 4];
    f32x4 s0 = __builtin_amdgcn_mfma_f32_16x16x32_f16(kf0, bq16, c18, 0, 0, 0);
    f32x4 s1 = __builtin_amdgcn_mfma_f32_16x16x32_f16(kf1, bq16, c18, 0, 0, 0);
    f32x4 e0, e1;
#pragma unroll
    for (int r = 0; r < 4; ++r) {
      e0[r] = __builtin_amdgcn_exp2f(s0[r] + (float)me[r]);
      e1[r] = __builtin_amdgcn_exp2f(s1[r] + (float)mo[r]);
    }
    u32x4 pk;
#pragma unroll
    for (int r = 0; r < 4; ++r)
      pk[r] = __builtin_bit_cast(unsigned,
                                 __builtin_amdgcn_cvt_pkrtz(e0[r], e1[r]));
    half8 pa = __builtin_bit_cast(half8, pk);  // keys 8grp..8grp+7
    acc[0] = __builtin_amdgcn_mfma_f32_16x16x32_f16(pa, v0, acc[0], 0, 0, 0);
    acc[1] = __builtin_amdgcn_mfma_f32_16x16x32_f16(pa, v1, acc[1], 0, 0, 0);
    accL = __builtin_amdgcn_mfma_f32_16x16x32_f16(pa, vones, accL, 0, 0, 0);
    __syncthreads();
  }

  // accL[r] = full lsum for q = 4grp+r (same layout as acc) -- no shuffles
#pragma unroll
  for (int r = 0; r < 4; ++r) {
    float inv = 1.f / accL[r];
    int qrow = q0g + role * 16 + grp * 4 + r;
    size_t obase = ((size_t)b * NTOK + qrow) * CDIM + head * HD;
    ao16[obase + row16] = f2h(acc[0][r] * inv);
    ao16[obase + 16 + row16] = f2h(acc[1][r] * inv);
  }
}

// ---------------------------------------------------------------------------
// Output projection: round-12 structure.
// ---------------------------------------------------------------------------
__global__ __launch_bounds__(512, 4) void gemm_out16(
    const unsigned short* __restrict__ a16, const unsigned short* __restrict__ wp16,
    const float* __restrict__ bp, float* __restrict__ out) {
  __shared__ __align__(16) unsigned short SM[16384];
  unsigned short* Xs = SM;
  unsigned short* Ws = SM + 8192;
  int tid = threadIdx.x;
  int w = tid >> 6, l = tid & 63;
  int row16 = l & 15, grp = l >> 4;
  int bid = blockIdx.x;
  int xcd = bid & 7, local = bid >> 3;
  int jb = local & 1, mb = xcd * 16 + (local >> 1);
  int j0 = jb * 128, m0 = mb * 128;
  int wm = w >> 1, wn = w & 1;

  auto stg = [&](int nb, int kt) {
    int k0s = kt * 32;
    int row = w * 16 + (l >> 2);
    int ge = (((l & 3) * 16) ^ ((row & 3) << 4)) >> 1;
    gl_lds16(a16 + (size_t)(m0 + row) * 256 + k0s + ge, Xs + nb * 4096 + w * 512);
    gl_lds16(wp16 + (size_t)(j0 + row) * 256 + k0s + ge, Ws + nb * 4096 + w * 512);
  };
  auto off16 = [&](int row, int g) {
    return row * 32 + ((((g * 16) ^ ((row & 3) << 4))) >> 1);
  };

  stg(0, 0);
  __syncthreads();

  f32x4 acc[2][4];
#pragma unroll
  for (int i = 0; i < 2; ++i)
#pragma unroll
    for (int c = 0; c < 4; ++c) acc[i][c] = (f32x4){0.f, 0.f, 0.f, 0.f};

  for (int kt = 0; kt < 8; ++kt) {
    int cur = kt & 1;
    if (kt < 7) stg(cur ^ 1, kt + 1);
    half8 a0 = ldh8(Xs + cur * 4096 + off16(wm * 32 + row16, grp));
    half8 a1 = ldh8(Xs + cur * 4096 + off16(wm * 32 + 16 + row16, grp));
#pragma unroll
    for (int c = 0; c < 4; ++c) {
      half8 bh = ldh8(Ws + cur * 4096 + off16(wn * 64 + c * 16 + row16, grp));
      acc[0][c] = __builtin_amdgcn_mfma_f32_16x16x32_f16(a0, bh, acc[0][c], 0, 0, 0);
      acc[1][c] = __builtin_amdgcn_mfma_f32_16x16x32_f16(a1, bh, acc[1][c], 0, 0, 0);
    }
    __syncthreads();
  }

#pragma unroll
  for (int i = 0; i < 2; ++i) {
    int ng = m0 + wm * 32 + i * 16 + grp * 4;
#pragma unroll
    for (int c = 0; c < 4; ++c) {
      int jg = j0 + wn * 64 + c * 16 + row16;
      float bias = bp[jg];
#pragma unroll
      for (int r = 0; r < 4; ++r) {
        out[(size_t)(ng + r) * CDIM + jg] = acc[i][c][r] + bias;
      }
    }
  }
}

// ---------------------------------------------------------------------------
extern "C" void kernel_launch(void* const* d_in, const int* in_sizes, int n_in,
                              void* d_out, int out_size, void* d_ws,
                              size_t ws_size, hipStream_t stream) {
  const float* x = (const float*)d_in[0];
  const float* mask = (const float*)d_in[1];
  const float* affine = (const float*)d_in[2];
  const float* Wq = (const float*)d_in[3];
  const float* bq = (const float*)d_in[4];
  const float* Wkv = (const float*)d_in[5];
  const float* bkv = (const float*)d_in[6];
  const float* Wp = (const float*)d_in[7];
  const float* bp = (const float*)d_in[8];
  const float* atab = (const float*)d_in[9];
  float* out = (float*)d_out;

  const size_t bhnd = (size_t)BB * HEADS * NTOK * HD;  // 4,194,304
  unsigned short* q16 = (unsigned short*)d_ws;
  unsigned short* k16 = q16 + bhnd;
  unsigned short* vt16 = k16 + bhnd;
  unsigned short* x16 = vt16 + bhnd;     // aliased as ao16 after qkv
  unsigned short* wt16 = x16 + bhnd;     // 768*256
  unsigned short* wp16 = wt16 + 768 * 256;
  unsigned short* mF16 = wp16 + 256 * 256;     // 4*64*16384 u16 = 8MB
  float* bias = (float*)(mF16 + (size_t)4 * 64 * 16384);

  prep_xwb<<<3136, 256, 0, stream>>>(x, Wq, Wkv, Wp, affine, atab, x16, wt16,
                                     wp16, bias);
  gemm_qkv16<<<2816, 512, 0, stream>>>(x16, wt16, bq, bkv, bias, mask, q16,
                                       k16, vt16, mF16);
  attn16<<<1024, 512, 0, stream>>>(q16, k16, vt16, mF16, x16);
  gemm_out16<<<256, 512, 0, stream>>>(x16, wp16, bp, out);
}

// Round 26
// 82.499 us; speedup vs baseline: 1.0396x; 1.0206x over previous
//
#include <hip/hip_runtime.h>
#include <hip/hip_bf16.h>
#include <math.h>

#define BB 16
#define NTOK 1024
#define CDIM 256
#define HEADS 8
#define HD 32
#define LOG2E 1.4426950408889634f
#define PSHIFT 18.0f

typedef __attribute__((ext_vector_type(8))) _Float16 half8;
typedef __attribute__((ext_vector_type(8))) unsigned short u16x8;
typedef __attribute__((ext_vector_type(4))) unsigned int u32x4;
typedef __attribute__((ext_vector_type(4))) float f32x4;

__device__ __forceinline__ unsigned short f2h(float f) {
  _Float16 h = (_Float16)f;
  return __builtin_bit_cast(unsigned short, h);
}
__device__ __forceinline__ half8 ldh8(const unsigned short* p) {
  return *reinterpret_cast<const half8*>(p);
}
__device__ __forceinline__ void gl_lds16(const void* g, void* l) {
  __builtin_amdgcn_global_load_lds(
      (const __attribute__((address_space(1))) unsigned int*)g,
      (__attribute__((address_space(3))) unsigned int*)l, 16, 0, 0);
}

// ---------------------------------------------------------------------------
// prep_xwb: producers qkv needs. [0,2048): cvt X; [2048,3072): cvt+T W;
// [3072,3136): angle bias.
// ---------------------------------------------------------------------------
__global__ __launch_bounds__(256) void prep_xwb(
    const float* __restrict__ X, const float* __restrict__ Wq,
    const float* __restrict__ Wkv, const float* __restrict__ Wp,
    const float* __restrict__ affine, const float* __restrict__ atab,
    unsigned short* __restrict__ x16, unsigned short* __restrict__ wt16,
    unsigned short* __restrict__ wp16, float* __restrict__ bias) {
  int bid = blockIdx.x;
  if (bid < 2048) {  // ---- cvt X (8/thread)
    size_t base = ((size_t)bid * 256 + threadIdx.x) * 8;
    float4 a = *(const float4*)(X + base);
    float4 b = *(const float4*)(X + base + 4);
    u16x8 o = {f2h(a.x), f2h(a.y), f2h(a.z), f2h(a.w),
               f2h(b.x), f2h(b.y), f2h(b.z), f2h(b.w)};
    *(u16x8*)(x16 + base) = o;
  } else if (bid < 3072) {  // ---- cvt + transpose W
    int idx = (bid - 2048) * 256 + threadIdx.x;
    float val; size_t dst; bool isp = false;
    if (idx < 65536) {
      int k = idx >> 8, n = idx & 255;
      val = Wq[idx]; dst = (size_t)n * 256 + k;
    } else if (idx < 196608) {
      int i2 = idx - 65536;
      int k = i2 >> 9, n2 = i2 & 511;
      val = Wkv[i2]; dst = (size_t)(256 + n2) * 256 + k;
    } else {
      int i3 = idx - 196608;
      int k = i3 >> 8, n = i3 & 255;
      val = Wp[i3]; dst = (size_t)n * 256 + k; isp = true;
    }
    unsigned short h = f2h(val);
    if (isp) wp16[dst] = h; else wt16[dst] = h;
  } else {  // ---- angle bias
    int idx = (bid - 3072) * 256 + threadIdx.x;
    if (idx >= BB * NTOK) return;
    int b = idx >> 10, n = idx & (NTOK - 1);
    float cx = (float)(n & 31);
    float cy = (float)(n >> 5);
    const float* A = affine + b * 6;
    float egx = fmaf(A[0], 16.f, fmaf(A[1], 16.f, A[2]));
    float egy = fmaf(A[3], 16.f, fmaf(A[4], 16.f, A[5]));
    float ang = atan2f(cy - egy, cx - egx);
    float t = (ang + 3.14159265358979323846f) *
              (1.f / (2.f * 3.14159265358979323846f)) * 4.f;
    int bin = (int)t;
    bin = bin < 0 ? 0 : (bin > 4 ? 4 : bin);
    for (int h = 0; h < HEADS; ++h) {
      float a = atab[bin * HEADS + h];
      float s = 1.f / (1.f + __expf(-a));
      bias[((size_t)b * HEADS + h) * NTOK + n] = 1.f + s;
    }
  }
}

// ---------------------------------------------------------------------------
// QKV projection FUSED with mask-fragment prep:
//  blocks [0,768): fp16 MFMA GEMM; [768,2816): mask -> f32 fragment slabs
//  (value = m*log2e - PSHIFT, C-operand-ready; slab = b4*64 + kt*2 + parity;
//   within slab addr = q*16 + (k&31)/2, fully linear -> linear attn DMA).
// ---------------------------------------------------------------------------
__global__ __launch_bounds__(512, 4) void gemm_qkv16(
    const unsigned short* __restrict__ x16, const unsigned short* __restrict__ wt16,
    const float* __restrict__ bq, const float* __restrict__ bkv,
    const float* __restrict__ bias, const float* __restrict__ mask,
    unsigned short* __restrict__ q16, unsigned short* __restrict__ k16,
    unsigned short* __restrict__ vt16, float* __restrict__ mF32) {
  __shared__ __align__(16) unsigned short SM[16384];  // 32 KB multi-use
  int bid = blockIdx.x;
  if (bid >= 768) {  // ---- mask prep branch (1 float4/thread, 512 thr)
    int idx = (bid - 768) * 512 + threadIdx.x;   // 0 .. 1,048,575
    int b4 = idx >> 18;
    int rem = idx & 262143;
    int q = rem >> 8;
    int k = (rem & 255) * 4;
    float4 v = *(const float4*)(mask + ((size_t)b4 * NTOK + q) * NTOK + k);
    int kt = k >> 5;
    size_t off = (size_t)q * 16 + ((k & 31) >> 1);
    size_t slabE = ((size_t)(b4 * 64 + kt * 2)) * 16384;
    float2 e = {fmaf(v.x, LOG2E, -PSHIFT), fmaf(v.z, LOG2E, -PSHIFT)};
    float2 o = {fmaf(v.y, LOG2E, -PSHIFT), fmaf(v.w, LOG2E, -PSHIFT)};
    *(float2*)(mF32 + slabE + off) = e;
    *(float2*)(mF32 + slabE + 16384 + off) = o;
    return;
  }
  unsigned short* Xs = SM;            // [2][4096]
  unsigned short* Ws = SM + 8192;     // [2][4096]
  int tid = threadIdx.x;
  int w = tid >> 6, l = tid & 63;
  int row16 = l & 15, grp = l >> 4;
  int xcd = bid & 7, local = bid >> 3;        // 0..95
  int jb = local % 6, mb = xcd * 16 + local / 6;
  int j0 = jb * 128, m0 = mb * 128;
  int wm = w >> 1, wn = w & 1;

  auto stg = [&](int nb, int kt) {  // 1KB chunk per operand per wave
    int k0s = kt * 32;
    int row = w * 16 + (l >> 2);
    int ge = (((l & 3) * 16) ^ ((row & 3) << 4)) >> 1;
    gl_lds16(x16 + (size_t)(m0 + row) * 256 + k0s + ge, Xs + nb * 4096 + w * 512);
    gl_lds16(wt16 + (size_t)(j0 + row) * 256 + k0s + ge, Ws + nb * 4096 + w * 512);
  };
  auto off16 = [&](int row, int g) {
    return row * 32 + ((((g * 16) ^ ((row & 3) << 4))) >> 1);
  };

  stg(0, 0);
  __syncthreads();

  f32x4 acc[2][4];
#pragma unroll
  for (int i = 0; i < 2; ++i)
#pragma unroll
    for (int c = 0; c < 4; ++c) acc[i][c] = (f32x4){0.f, 0.f, 0.f, 0.f};

  for (int kt = 0; kt < 8; ++kt) {
    int cur = kt & 1;
    if (kt < 7) stg(cur ^ 1, kt + 1);
    half8 a0 = ldh8(Xs + cur * 4096 + off16(wm * 32 + row16, grp));
    half8 a1 = ldh8(Xs + cur * 4096 + off16(wm * 32 + 16 + row16, grp));
#pragma unroll
    for (int c = 0; c < 4; ++c) {
      half8 bh = ldh8(Ws + cur * 4096 + off16(wn * 64 + c * 16 + row16, grp));
      acc[0][c] = __builtin_amdgcn_mfma_f32_16x16x32_f16(a0, bh, acc[0][c], 0, 0, 0);
      acc[1][c] = __builtin_amdgcn_mfma_f32_16x16x32_f16(a1, bh, acc[1][c], 0, 0, 0);
    }
    __syncthreads();
  }

  // epilogue: bounce through SM as u16 [64][136], two 64-row halves
  const float scaleq = 0.17677669529663687f * LOG2E;
  int half_mine = wm >> 1;
  for (int half = 0; half < 2; ++half) {
    if (half_mine == half) {
#pragma unroll
      for (int i = 0; i < 2; ++i) {
#pragma unroll
        for (int c = 0; c < 4; ++c) {
          int col = wn * 64 + c * 16 + row16;
          int jg = j0 + col;
#pragma unroll
          for (int r = 0; r < 4; ++r) {
            int rowl = (wm & 1) * 32 + i * 16 + grp * 4 + r;
            int m = m0 + half * 64 + rowl;
            int b = m >> 10, n = m & (NTOK - 1);
            float val = acc[i][c][r];
            unsigned short o;
            if (jb < 2)
              o = f2h((val + bq[jg]) * scaleq *
                      bias[((size_t)b * HEADS + (jg >> 5)) * NTOK + n]);
            else
              o = f2h(val + bkv[jg - CDIM]);
            SM[rowl * 136 + col] = o;
          }
        }
      }
    }
    __syncthreads();
    if (jb < 4) {
#pragma unroll
      for (int it = 0; it < 2; ++it) {
        int lin = it * 512 + tid;
        int rowb = lin >> 4, oct = lin & 15;
        u16x8 v = *(const u16x8*)&SM[rowb * 136 + oct * 8];
        int m = m0 + half * 64 + rowb;
        int b = m >> 10, n = m & (NTOK - 1);
        int jg = j0 + oct * 8;
        unsigned short* dst; int h, d;
        if (jb < 2) { h = jg >> 5; d = jg & 31; dst = q16; }
        else { int c2 = jg - CDIM; h = c2 >> 5; d = c2 & 31; dst = k16; }
        *(u16x8*)(dst + (((size_t)b * HEADS + h) * NTOK + n) * HD + d) = v;
      }
    } else {
#pragma unroll
      for (int it = 0; it < 2; ++it) {
        int lin = it * 512 + tid;
        int noct = lin >> 7, jl = lin & 127;
        u16x8 v;
#pragma unroll
        for (int e = 0; e < 8; ++e) v[e] = SM[(noct * 8 + e) * 136 + jl];
        int c3 = j0 + jl - 2 * CDIM;
        int h = c3 >> 5, d = c3 & 31;
        int n0 = m0 + half * 64 + noct * 8;
        int b = n0 >> 10, nn = n0 & (NTOK - 1);
        *(u16x8*)(vt16 + (((size_t)b * HEADS + h) * HD + d) * NTOK + nn) = v;
      }
    }
    __syncthreads();
  }
}

// ---------------------------------------------------------------------------
// Flash attention (R24/25 structure: head-group of 2, grid 1024, MFMA lsum)
// with the mask as a f32 MFMA C-operand (zero VALU mask cost):
//   s = mfma(kf, bq, mC) already includes m*log2e - PSHIFT.
// MT: [buf][slab][64q x 16 f32] staged linearly by all 8 waves.
// ---------------------------------------------------------------------------
__global__ __launch_bounds__(512, 8) void attn16(
    const unsigned short* __restrict__ q16, const unsigned short* __restrict__ k16,
    const unsigned short* __restrict__ vt16, const float* __restrict__ mF32,
    unsigned short* __restrict__ ao16) {
  __shared__ __align__(16) unsigned short KT[2][2][1024];  // [buf][head][32k x 32d]
  __shared__ __align__(16) unsigned short VT[2][2][1024];  // [buf][head][32d x 32k]
  __shared__ __align__(16) float MT[2][2][1024];           // [buf][slab][64q x 16]

  int tid = threadIdx.x;
  int w = tid >> 6, l = tid & 63;
  int row16 = l & 15, grp = l >> 4;
  int bid = blockIdx.x;
  int g = (bid >> 7) * 8 + (bid & 7);
  int inner = (bid >> 3) & 15;
  int qt = g >> 2, b4 = g & 3;
  int brep = inner >> 2, hg = inner & 3;
  int b = brep * 4 + b4;
  int hl = w & 1, role = w >> 1;
  int head = hg * 2 + hl;
  int bh = b * HEADS + head;
  int q0g = qt * 64;

  // Q B-operand: this wave's 16-q fragment
  half8 bq16 = ldh8(q16 + ((size_t)bh * NTOK + q0g + role * 16 + row16) * HD +
                    grp * 8);

  const float* mFb = mF32 + (size_t)b4 * 64 * 16384;

  f32x4 acc[2];
  acc[0] = (f32x4){0.f, 0.f, 0.f, 0.f};
  acc[1] = (f32x4){0.f, 0.f, 0.f, 0.f};
  f32x4 accL = (f32x4){0.f, 0.f, 0.f, 0.f};   // lsum per q (MFMA-accumulated)
  const _Float16 one = (_Float16)1.0f;
  const half8 vones = {one, one, one, one, one, one, one, one};

  auto off32 = [&](int row, int gg) {
    return row * 32 + ((gg ^ ((row >> 1) & 3)) << 3);
  };

  auto stage = [&](int nb, int kt2) {
    int k0n = (kt2 & 31) * 32;
    if (role < 2) {  // K chunk c = role: LDS row r = c*16+(l>>2), key 2*(l>>2)+c
      int c = role;
      int r = c * 16 + (l >> 2);
      int key = 2 * (l >> 2) + c;
      int sk = (l & 3) ^ ((r >> 1) & 3);
      gl_lds16(k16 + ((size_t)bh * NTOK + k0n + key) * HD + sk * 8,
               &KT[nb][hl][c * 512]);
    } else {         // V chunk c = role-2: d-rows c*16..+15
      int c = role - 2;
      int dl = c * 16 + (l >> 2);
      int sv = (l & 3) ^ ((dl >> 1) & 3);
      gl_lds16(vt16 + ((size_t)bh * HD + dl) * NTOK + k0n + sv * 8,
               &VT[nb][hl][c * 512]);
    }
    // mask: all 8 waves stage one 1KB chunk (2 slabs x 4 chunks), linear
    {
      int slab = w >> 2, ch = w & 3;
      gl_lds16(mFb + (size_t)((kt2 & 31) * 2 + slab) * 16384 + q0g * 16 +
                   ch * 256 + l * 4,
               &MT[nb][slab][ch * 256]);
    }
  };

  stage(0, 0);
  __syncthreads();

  for (int kt = 0; kt < 32; ++kt) {
    int cur = kt & 1;
    if (kt < 31) stage(cur ^ 1, kt + 1);

    half8 kf0 = ldh8(&KT[cur][hl][off32(row16, grp)]);
    half8 kf1 = ldh8(&KT[cur][hl][off32(16 + row16, grp)]);
    half8 v0 = ldh8(&VT[cur][hl][off32(row16, grp)]);
    half8 v1 = ldh8(&VT[cur][hl][off32(16 + row16, grp)]);

    int qr = role * 16 + row16;                    // local q row 0..63
    f32x4 mC0 = *(const f32x4*)&MT[cur][0][qr * 16 + grp * 4];
    f32x4 mC1 = *(const f32x4*)&MT[cur][1][qr * 16 + grp * 4];
    f32x4 s0 = __builtin_amdgcn_mfma_f32_16x16x32_f16(kf0, bq16, mC0, 0, 0, 0);
    f32x4 s1 = __builtin_amdgcn_mfma_f32_16x16x32_f16(kf1, bq16, mC1, 0, 0, 0);
    f32x4 e0, e1;
#pragma unroll
    for (int r = 0; r < 4; ++r) {
      e0[r] = __builtin_amdgcn_exp2f(s0[r]);
      e1[r] = __builtin_amdgcn_exp2f(s1[r]);
    }
    u32x4 pk;
#pragma unroll
    for (int r = 0; r < 4; ++r)
      pk[r] = __builtin_bit_cast(unsigned,
                                 __builtin_amdgcn_cvt_pkrtz(e0[r], e1[r]));
    half8 pa = __builtin_bit_cast(half8, pk);  // keys 8grp..8grp+7
    acc[0] = __builtin_amdgcn_mfma_f32_16x16x32_f16(pa, v0, acc[0], 0, 0, 0);
    acc[1] = __builtin_amdgcn_mfma_f32_16x16x32_f16(pa, v1, acc[1], 0, 0, 0);
    accL = __builtin_amdgcn_mfma_f32_16x16x32_f16(pa, vones, accL, 0, 0, 0);
    __syncthreads();
  }

  // accL[r] = full lsum for q = 4grp+r (same layout as acc) -- no shuffles
#pragma unroll
  for (int r = 0; r < 4; ++r) {
    float inv = 1.f / accL[r];
    int qrow = q0g + role * 16 + grp * 4 + r;
    size_t obase = ((size_t)b * NTOK + qrow) * CDIM + head * HD;
    ao16[obase + row16] = f2h(acc[0][r] * inv);
    ao16[obase + 16 + row16] = f2h(acc[1][r] * inv);
  }
}

// ---------------------------------------------------------------------------
// Output projection: round-12 structure.
// ---------------------------------------------------------------------------
__global__ __launch_bounds__(512, 4) void gemm_out16(
    const unsigned short* __restrict__ a16, const unsigned short* __restrict__ wp16,
    const float* __restrict__ bp, float* __restrict__ out) {
  __shared__ __align__(16) unsigned short SM[16384];
  unsigned short* Xs = SM;
  unsigned short* Ws = SM + 8192;
  int tid = threadIdx.x;
  int w = tid >> 6, l = tid & 63;
  int row16 = l & 15, grp = l >> 4;
  int bid = blockIdx.x;
  int xcd = bid & 7, local = bid >> 3;
  int jb = local & 1, mb = xcd * 16 + (local >> 1);
  int j0 = jb * 128, m0 = mb * 128;
  int wm = w >> 1, wn = w & 1;

  auto stg = [&](int nb, int kt) {
    int k0s = kt * 32;
    int row = w * 16 + (l >> 2);
    int ge = (((l & 3) * 16) ^ ((row & 3) << 4)) >> 1;
    gl_lds16(a16 + (size_t)(m0 + row) * 256 + k0s + ge, Xs + nb * 4096 + w * 512);
    gl_lds16(wp16 + (size_t)(j0 + row) * 256 + k0s + ge, Ws + nb * 4096 + w * 512);
  };
  auto off16 = [&](int row, int g) {
    return row * 32 + ((((g * 16) ^ ((row & 3) << 4))) >> 1);
  };

  stg(0, 0);
  __syncthreads();

  f32x4 acc[2][4];
#pragma unroll
  for (int i = 0; i < 2; ++i)
#pragma unroll
    for (int c = 0; c < 4; ++c) acc[i][c] = (f32x4){0.f, 0.f, 0.f, 0.f};

  for (int kt = 0; kt < 8; ++kt) {
    int cur = kt & 1;
    if (kt < 7) stg(cur ^ 1, kt + 1);
    half8 a0 = ldh8(Xs + cur * 4096 + off16(wm * 32 + row16, grp));
    half8 a1 = ldh8(Xs + cur * 4096 + off16(wm * 32 + 16 + row16, grp));
#pragma unroll
    for (int c = 0; c < 4; ++c) {
      half8 bh = ldh8(Ws + cur * 4096 + off16(wn * 64 + c * 16 + row16, grp));
      acc[0][c] = __builtin_amdgcn_mfma_f32_16x16x32_f16(a0, bh, acc[0][c], 0, 0, 0);
      acc[1][c] = __builtin_amdgcn_mfma_f32_16x16x32_f16(a1, bh, acc[1][c], 0, 0, 0);
    }
    __syncthreads();
  }

#pragma unroll
  for (int i = 0; i < 2; ++i) {
    int ng = m0 + wm * 32 + i * 16 + grp * 4;
#pragma unroll
    for (int c = 0; c < 4; ++c) {
      int jg = j0 + wn * 64 + c * 16 + row16;
      float bias = bp[jg];
#pragma unroll
      for (int r = 0; r < 4; ++r) {
        out[(size_t)(ng + r) * CDIM + jg] = acc[i][c][r] + bias;
      }
    }
  }
}

// ---------------------------------------------------------------------------
extern "C" void kernel_launch(void* const* d_in, const int* in_sizes, int n_in,
                              void* d_out, int out_size, void* d_ws,
                              size_t ws_size, hipStream_t stream) {
  const float* x = (const float*)d_in[0];
  const float* mask = (const float*)d_in[1];
  const float* affine = (const float*)d_in[2];
  const float* Wq = (const float*)d_in[3];
  const float* bq = (const float*)d_in[4];
  const float* Wkv = (const float*)d_in[5];
  const float* bkv = (const float*)d_in[6];
  const float* Wp = (const float*)d_in[7];
  const float* bp = (const float*)d_in[8];
  const float* atab = (const float*)d_in[9];
  float* out = (float*)d_out;

  const size_t bhnd = (size_t)BB * HEADS * NTOK * HD;  // 4,194,304
  unsigned short* q16 = (unsigned short*)d_ws;
  unsigned short* k16 = q16 + bhnd;
  unsigned short* vt16 = k16 + bhnd;
  unsigned short* x16 = vt16 + bhnd;     // aliased as ao16 after qkv
  unsigned short* wt16 = x16 + bhnd;     // 768*256
  unsigned short* wp16 = wt16 + 768 * 256;
  float* mF32 = (float*)(wp16 + 256 * 256);    // 4*64*16384 f32 = 16MB
  float* bias = mF32 + (size_t)4 * 64 * 16384;

  prep_xwb<<<3136, 256, 0, stream>>>(x, Wq, Wkv, Wp, affine, atab, x16, wt16,
                                     wp16, bias);
  gemm_qkv16<<<2816, 512, 0, stream>>>(x16, wt16, bq, bkv, bias, mask, q16,
                                       k16, vt16, mF32);
  attn16<<<1024, 512, 0, stream>>>(q16, k16, vt16, mF32, x16);
  gemm_out16<<<256, 512, 0, stream>>>(x16, wp16, bp, out);
}